// Round 1
// baseline (226.402 us; speedup 1.0000x reference)
//
#include <hip/hip_runtime.h>
#include <hip/hip_bf16.h>

#define BB 32
#define PP 1024
#define HID 512
#define NH 8
#define DD 64
#define MEM 64
#define RANK 64

// Workspace layout (floats)
#define A_OFF   0          // [8][64]
#define M_OFF   512        // [17][17]
#define T_OFF   1024       // [32][8][64]
#define S1_OFF  17408      // [32][8]
#define S2_OFF  17664      // [32][8]
#define G_OFF   18432      // [32][16][1024]
#define F_OFF   542720     // [32][17][1024]

// ---------------------------------------------------------------------------
// Kernel 1: tiny precompute. A[h][m] = w_k[h,:]·w_mem[m,:];
// WU[j][r]/WV[j][r] (17x64 each, in LDS); M17[i][j] = Σ_r WU[i][r]*WV[j][r].
// ---------------------------------------------------------------------------
__global__ __launch_bounds__(1024) void k_precompute(
    const float* __restrict__ wk, const float* __restrict__ wmem,
    const float* __restrict__ wv, const float* __restrict__ bv,
    const float* __restrict__ wu, const float* __restrict__ bu,
    const float* __restrict__ wv2, const float* __restrict__ bv2,
    float* __restrict__ A, float* __restrict__ M17) {
  __shared__ float WU[17 * 64];
  __shared__ float WV[17 * 64];
  const int t = threadIdx.x;

  if (t < 512) {
    const int h = t >> 6, m = t & 63;
    float s = 0.f;
    for (int d = 0; d < DD; ++d) s += wk[h * DD + d] * wmem[m * DD + d];
    A[t] = s;
  }

  for (int i = t; i < 17 * 64; i += 1024) {
    const int j = i >> 6, r = i & 63;
    float su = 0.f, sv = 0.f;
    if (j < 8) {
      for (int d = 0; d < DD; ++d) {
        const float w = wv[j * DD + d];
        su += wu[r * HID + j * DD + d] * w;
        sv += wv2[r * HID + j * DD + d] * w;
      }
    } else if (j < 16) {
      const int h = j - 8;
      for (int d = 0; d < DD; ++d) {
        const float w = bv[h * DD + d];
        su += wu[r * HID + h * DD + d] * w;
        sv += wv2[r * HID + h * DD + d] * w;
      }
    } else {
      su = bu[r];
      sv = bv2[r];
    }
    WU[i] = su;
    WV[i] = sv;
  }
  __syncthreads();

  if (t < 17 * 17) {
    const int i = t / 17, j = t % 17;
    float s = 0.f;
    for (int r = 0; r < 64; ++r) s += WU[i * 64 + r] * WV[j * 64 + r];
    M17[t] = s;
  }
}

// ---------------------------------------------------------------------------
// Kernel 2: T[b,h,m] = softmax_p(x[b,p]*A[h,m]) weighted mean of x.
// One wave per (b,h,m) task; 16384 tasks; 4 waves per block.
// ---------------------------------------------------------------------------
__global__ __launch_bounds__(256) void k_memsoftmax(
    const float* __restrict__ x, const float* __restrict__ A,
    float* __restrict__ T) {
  const int wid = blockIdx.x * 4 + (threadIdx.x >> 6);   // [0, 16384)
  const int lane = threadIdx.x & 63;
  const int b = wid >> 9;
  const int hm = wid & 511;               // h*64+m
  const float a = A[hm];
  const float* xr = x + b * PP;

  float xs[16];
  float mx = -INFINITY;
#pragma unroll
  for (int k = 0; k < 16; ++k) {
    xs[k] = xr[lane + k * 64];
    mx = fmaxf(mx, xs[k] * a);
  }
#pragma unroll
  for (int off = 32; off >= 1; off >>= 1) mx = fmaxf(mx, __shfl_xor(mx, off));

  float s = 0.f, sx = 0.f;
#pragma unroll
  for (int k = 0; k < 16; ++k) {
    const float e = __expf(xs[k] * a - mx);
    s += e;
    sx += e * xs[k];
  }
#pragma unroll
  for (int off = 32; off >= 1; off >>= 1) {
    s += __shfl_xor(s, off);
    sx += __shfl_xor(sx, off);
  }
  if (lane == 0) T[wid] = sx / s;
}

// ---------------------------------------------------------------------------
// Kernel 3: S1[b,h] = Σ_m T, S2[b,h] = Σ_m T². 256 (b,h) tasks, 1 block.
// ---------------------------------------------------------------------------
__global__ __launch_bounds__(256) void k_tsums(
    const float* __restrict__ T, float* __restrict__ S1,
    float* __restrict__ S2) {
  const int t = threadIdx.x;  // (b*8+h)
  const float* Tr = T + t * MEM;
  float s1 = 0.f, s2 = 0.f;
  for (int m = 0; m < MEM; ++m) {
    const float v = Tr[m];
    s1 += v;
    s2 += v * v;
  }
  S1[t] = s1;
  S2[t] = s2;
}

// ---------------------------------------------------------------------------
// Kernel 4: per (b,h,p): a1 = Σ_d φ(x*wq+bq)*wv, a0 = Σ_d φ(...)*bv;
// c1 = a1*S2 + a0*S1 -> G[b][h][p];  c2 = a1*S1 + a0*M -> G[b][8+h][p].
// h uniform per block (block = 256 consecutive p within one (b,h)).
// ---------------------------------------------------------------------------
__global__ __launch_bounds__(256) void k_features(
    const float* __restrict__ x, const float* __restrict__ wq,
    const float* __restrict__ bq, const float* __restrict__ wv,
    const float* __restrict__ bv, const float* __restrict__ S1,
    const float* __restrict__ S2, float* __restrict__ G) {
  const int idx0 = blockIdx.x * 256;
  const int b = idx0 >> 13;
  const int h = (idx0 >> 10) & 7;
  const int p = (idx0 & 1023) + threadIdx.x;

  const float xv = x[b * PP + p];
  float a1 = 0.f, a0 = 0.f;
#pragma unroll 8
  for (int d = 0; d < DD; ++d) {
    const float q = xv * wq[h * DD + d] + bq[h * DD + d];
    const float ph = (q > 0.f) ? (q + 1.f) : __expf(q);
    a1 += ph * wv[h * DD + d];
    a0 += ph * bv[h * DD + d];
  }
  const float s1 = S1[b * 8 + h], s2 = S2[b * 8 + h];
  const float c1 = a1 * s2 + a0 * s1;
  const float c2 = a1 * s1 + a0 * (float)MEM;
  G[(b * 16 + h) * PP + p] = c1;
  G[(b * 16 + 8 + h) * PP + p] = c2;
}

// ---------------------------------------------------------------------------
// Kernel 5: F[b][j][p] = M17[16][j] + Σ_{i<16} G[b][i][p]*M17[i][j].
// ---------------------------------------------------------------------------
__global__ __launch_bounds__(256) void k_fmap(
    const float* __restrict__ G, const float* __restrict__ M17,
    float* __restrict__ F) {
  __shared__ float Ml[17 * 17];
  const int t = threadIdx.x;
  for (int i = t; i < 17 * 17; i += 256) Ml[i] = M17[i];
  __syncthreads();

  const int idx = blockIdx.x * 256 + t;  // [0, 32768)
  const int b = idx >> 10, p = idx & 1023;
  float g[16];
#pragma unroll
  for (int i = 0; i < 16; ++i) g[i] = G[(b * 16 + i) * PP + p];
#pragma unroll
  for (int j = 0; j < 17; ++j) {
    float f = Ml[16 * 17 + j];
#pragma unroll
    for (int i = 0; i < 16; ++i) f += g[i] * Ml[i * 17 + j];
    F[(b * 17 + j) * PP + p] = f;
  }
}

// ---------------------------------------------------------------------------
// Kernel 6: out[b,p,q] = F[b][16][p] + Σ_{j<16} F[b][j][p]*G[b][j][q].
// 64x64 tile per block, 256 threads, thread computes 4p x 4q (float4 stores).
// ---------------------------------------------------------------------------
__global__ __launch_bounds__(256) void k_coeffs(
    const float* __restrict__ F, const float* __restrict__ G,
    float* __restrict__ out) {
  __shared__ float Fl[17 * 64];
  __shared__ float Gl[16 * 64];
  const int b = blockIdx.z;
  const int p0 = blockIdx.y * 64;
  const int q0 = blockIdx.x * 64;
  const int t = threadIdx.x;

  const float* Fg = F + (size_t)b * 17 * PP;
  const float* Gg = G + (size_t)b * 16 * PP;
  for (int i = t; i < 17 * 64; i += 256) Fl[i] = Fg[(i >> 6) * PP + p0 + (i & 63)];
  for (int i = t; i < 16 * 64; i += 256) Gl[i] = Gg[(i >> 6) * PP + q0 + (i & 63)];
  __syncthreads();

  const int pr = t >> 4;   // 0..15  -> p rows pr*4 .. pr*4+3
  const int qv = t & 15;   // 0..15  -> q cols qv*4 .. qv*4+3

  const float4 f16 = *(const float4*)&Fl[16 * 64 + pr * 4];
  float4 acc0 = make_float4(f16.x, f16.x, f16.x, f16.x);
  float4 acc1 = make_float4(f16.y, f16.y, f16.y, f16.y);
  float4 acc2 = make_float4(f16.z, f16.z, f16.z, f16.z);
  float4 acc3 = make_float4(f16.w, f16.w, f16.w, f16.w);

#pragma unroll
  for (int j = 0; j < 16; ++j) {
    const float4 fj = *(const float4*)&Fl[j * 64 + pr * 4];
    const float4 gj = *(const float4*)&Gl[j * 64 + qv * 4];
    acc0.x += fj.x * gj.x; acc0.y += fj.x * gj.y; acc0.z += fj.x * gj.z; acc0.w += fj.x * gj.w;
    acc1.x += fj.y * gj.x; acc1.y += fj.y * gj.y; acc1.z += fj.y * gj.z; acc1.w += fj.y * gj.w;
    acc2.x += fj.z * gj.x; acc2.y += fj.z * gj.y; acc2.z += fj.z * gj.z; acc2.w += fj.z * gj.w;
    acc3.x += fj.w * gj.x; acc3.y += fj.w * gj.y; acc3.z += fj.w * gj.z; acc3.w += fj.w * gj.w;
  }

  const size_t base = ((size_t)(b * PP + p0 + pr * 4)) * PP + q0 + qv * 4;
  *(float4*)&out[base] = acc0;
  *(float4*)&out[base + PP] = acc1;
  *(float4*)&out[base + 2 * PP] = acc2;
  *(float4*)&out[base + 3 * PP] = acc3;
}

extern "C" void kernel_launch(void* const* d_in, const int* in_sizes, int n_in,
                              void* d_out, int out_size, void* d_ws, size_t ws_size,
                              hipStream_t stream) {
  const float* x    = (const float*)d_in[0];
  const float* wq   = (const float*)d_in[1];
  const float* bq   = (const float*)d_in[2];
  const float* wk   = (const float*)d_in[3];
  const float* bk   = (const float*)d_in[4];  (void)bk;  // drops out of softmax
  const float* wv   = (const float*)d_in[5];
  const float* bv   = (const float*)d_in[6];
  const float* wmem = (const float*)d_in[7];
  const float* wu   = (const float*)d_in[8];
  const float* bu   = (const float*)d_in[9];
  const float* wv2  = (const float*)d_in[10];
  const float* bv2  = (const float*)d_in[11];

  float* ws = (float*)d_ws;
  float* A   = ws + A_OFF;
  float* M17 = ws + M_OFF;
  float* T   = ws + T_OFF;
  float* S1  = ws + S1_OFF;
  float* S2  = ws + S2_OFF;
  float* G   = ws + G_OFF;
  float* F   = ws + F_OFF;
  float* out = (float*)d_out;

  k_precompute<<<1, 1024, 0, stream>>>(wk, wmem, wv, bv, wu, bu, wv2, bv2, A, M17);
  k_memsoftmax<<<4096, 256, 0, stream>>>(x, A, T);
  k_tsums<<<1, 256, 0, stream>>>(T, S1, S2);
  k_features<<<1024, 256, 0, stream>>>(x, wq, bq, wv, bv, S1, S2, G);
  k_fmap<<<128, 256, 0, stream>>>(G, M17, F);
  k_coeffs<<<dim3(16, 16, 32), 256, 0, stream>>>(F, G, out);
}